// Round 7
// baseline (475.305 us; speedup 1.0000x reference)
//
#include <hip/hip_runtime.h>
#include <math.h>

#define NAn 40000
#define NBn 40000
#define DIN 256
#define DOUT 256
#define NH 8
#define NC 32
#define NE 400000
#define CAP 64
#define GEMMB ((NAn + NBn) / 64)          // 1250 gemm blocks
#define CSRB ((3 * NE + 255) / 256)       // 4688 csr blocks

typedef __attribute__((ext_vector_type(8))) short short8;
typedef __attribute__((ext_vector_type(4))) float floatx4;

__device__ __forceinline__ float leaky(float x) { return x > 0.f ? x : 0.2f * x; }
__device__ __forceinline__ unsigned bf16_rne_bits(float x) {
  unsigned u = __float_as_uint(x);
  unsigned r = u + 0x7fffu + ((u >> 16) & 1u);
  return r & 0xffff0000u;
}
__device__ __forceinline__ void bf8(uint4 u, float* f) {
  f[0] = __uint_as_float(u.x << 16);
  f[1] = __uint_as_float(u.x & 0xffff0000u);
  f[2] = __uint_as_float(u.y << 16);
  f[3] = __uint_as_float(u.y & 0xffff0000u);
  f[4] = __uint_as_float(u.z << 16);
  f[5] = __uint_as_float(u.z & 0xffff0000u);
  f[6] = __uint_as_float(u.w << 16);
  f[7] = __uint_as_float(u.w & 0xffff0000u);
}

// ---- W fp32 -> swizzled bf16 B-fragments (hi only; both matrices) -----------
// Also zeroes the 3*NAn csr counters (consumed by the csr half of gemm_csr,
// which only launches after this kernel completes).
__global__ void wswz(const float* __restrict__ WA, const float* __restrict__ WB,
                     short8* __restrict__ hiA, short8* __restrict__ hiB,
                     int* __restrict__ cnts) {
  int t = blockIdx.x * blockDim.x + threadIdx.x;
  for (int i = t; i < 3 * NAn; i += 16384) cnts[i] = 0;
  const float* W;
  short8* hi;
  int tt = t;
  if (tt < 8192) {
    W = WA; hi = hiA;
  } else {
    tt -= 8192;
    if (tt >= 8192) return;
    W = WB; hi = hiB;
  }
  int kt = tt >> 10, nt = (tt >> 6) & 15, l = tt & 63;
  int n = nt * 16 + (l & 15);
  int kb = kt * 32 + (l >> 4) * 8;
  short8 h8;
#pragma unroll
  for (int j = 0; j < 8; ++j) {
    float w = W[(size_t)(kb + j) * DOUT + n];
    h8[j] = (short)(bf16_rne_bits(w) >> 16);
  }
  hi[tt] = h8;
}

// ---- FUSED: edge bucketing (blocks 0..CSRB-1) + MFMA GEMM w/ alphas epilogue.
// csr first: its 4688 short blocks flood the CUs immediately and stream;
// gemm's 1250 LDS-limited blocks ride on the csr drain tail instead of
// blocking its head. launch_bounds(256,5) pins VGPR<=102 so the csr segment
// keeps 5 blocks/CU (20 waves) despite inheriting gemm's footprint.
__global__ __launch_bounds__(256, 5) void gemm_csr(
    const float* __restrict__ XA, const float* __restrict__ XB,
    const short8* __restrict__ WAhi, const short8* __restrict__ WBhi,
    const float* __restrict__ bA, const float* __restrict__ bB,
    const float* __restrict__ attn_l, const float* __restrict__ attn_r,
    unsigned* __restrict__ HAbf, unsigned* __restrict__ HBbf,
    float* __restrict__ al0, float* __restrict__ ar1,
    float* __restrict__ al2, float* __restrict__ ar2,
    float* __restrict__ ar0, float* __restrict__ al1,
    const int* __restrict__ e_ba, const int* __restrict__ e_aa,
    const int* __restrict__ e_ab, int* __restrict__ cnt_ba,
    int* __restrict__ cnt_aa, int* __restrict__ cnt_ab,
    int* __restrict__ sl_ba, int* __restrict__ sl_aa, int* __restrict__ sl_ab) {
  if (blockIdx.x < CSRB) {
    // ---------------- csr segment (short, no LDS use) ----------------
    int i = blockIdx.x * 256 + threadIdx.x;
    if (i >= 3 * NE) return;
    const int* e;
    int* cnt;
    int* sl;
    int k = i;
    if (i < NE) {
      e = e_ba; cnt = cnt_ba; sl = sl_ba;
    } else if (i < 2 * NE) {
      e = e_aa; cnt = cnt_aa; sl = sl_aa; k = i - NE;
    } else {
      e = e_ab; cnt = cnt_ab; sl = sl_ab; k = i - 2 * NE;
    }
    int src = e[k];
    int dst = e[NE + k];
    int pos = atomicAdd(&cnt[dst], 1);
    if (pos < CAP) sl[(size_t)dst * CAP + pos] = src;
    return;
  }
  // ---------------- gemm segment (hoisted-X R5 body + alphas epilogue) -------
  __shared__ short8 bfrag[2][1024];  // 2 x 16 KB (reused as h-tile in epilogue)
  int blk = blockIdx.x - CSRB;
  const bool isA = blk < (NAn / 64);
  const float* X;
  const short8* Wh;
  const float* bias;
  unsigned* Hbf;
  if (isA) {
    X = XA; Wh = WAhi; bias = bA; Hbf = HAbf;
  } else {
    blk -= NAn / 64;
    X = XB; Wh = WBhi; bias = bB; Hbf = HBbf;
  }
  const int tid = threadIdx.x;
  const int lane = tid & 63, wave = tid >> 6;
  const int col16 = lane & 15, quad = lane >> 4;
  const int row0 = blk * 64 + wave * 16;

  const float4* xp = (const float4*)(X + (size_t)(row0 + col16) * DIN) + quad * 2;
  const uint4* wsrc = (const uint4*)Wh;

  uint4 pre[4];
#pragma unroll
  for (int c = 0; c < 4; ++c) pre[c] = wsrc[c * 256 + tid];

  float4 xf[16];
#pragma unroll
  for (int j = 0; j < 16; ++j) xf[j] = xp[(j >> 1) * 8 + (j & 1)];

  {
    uint4* d = (uint4*)&bfrag[0][0];
#pragma unroll
    for (int c = 0; c < 4; ++c) d[c * 256 + tid] = pre[c];
  }

  short8 AH[8], AL[8];
#pragma unroll
  for (int kt = 0; kt < 8; ++kt) {
    float xv[8] = {xf[2 * kt].x,     xf[2 * kt].y,     xf[2 * kt].z,     xf[2 * kt].w,
                   xf[2 * kt + 1].x, xf[2 * kt + 1].y, xf[2 * kt + 1].z, xf[2 * kt + 1].w};
#pragma unroll
    for (int j = 0; j < 8; ++j) {
      unsigned hb = bf16_rne_bits(xv[j]);
      AH[kt][j] = (short)(hb >> 16);
      float rem = xv[j] - __uint_as_float(hb);
      AL[kt][j] = (short)(bf16_rne_bits(rem) >> 16);
    }
  }

  floatx4 acc[16];
#pragma unroll
  for (int i = 0; i < 16; ++i) acc[i] = (floatx4){0.f, 0.f, 0.f, 0.f};
  __syncthreads();

#pragma unroll
  for (int kt = 0; kt < 8; ++kt) {
    if (kt < 7) {
      const uint4* s = wsrc + (size_t)(kt + 1) * 1024;
#pragma unroll
      for (int c = 0; c < 4; ++c) pre[c] = s[c * 256 + tid];
    }
    const short8* bp = &bfrag[kt & 1][0];
#pragma unroll
    for (int nt = 0; nt < 16; ++nt) {
      short8 bv = bp[nt * 64 + lane];  // ds_read_b128
      acc[nt] = __builtin_amdgcn_mfma_f32_16x16x32_bf16(AH[kt], bv, acc[nt], 0, 0, 0);
      acc[nt] = __builtin_amdgcn_mfma_f32_16x16x32_bf16(AL[kt], bv, acc[nt], 0, 0, 0);
    }
    if (kt < 7) {
      uint4* d = (uint4*)&bfrag[(kt + 1) & 1][0];
#pragma unroll
      for (int c = 0; c < 4; ++c) d[c * 256 + tid] = pre[c];
    }
    __syncthreads();
  }
  // epilogue: C/D mapping col = lane&15, row = quad*4 + r.
  // Packed bf16 pairs to global AND to the (now free) LDS tile.
  unsigned* lds_u = (unsigned*)&bfrag[0][0];  // [64 rows][128 packed uints]
#pragma unroll
  for (int nt = 0; nt < 16; ++nt) {
    float bcol = bias[nt * 16 + col16];
#pragma unroll
    for (int r = 0; r < 4; ++r) {
      int rl = wave * 16 + quad * 4 + r;
      float v = acc[nt][r] + bcol;
      float vp = __shfl_xor(v, 1);
      if ((lane & 1) == 0) {
        unsigned p = (bf16_rne_bits(v) >> 16) | bf16_rne_bits(vp);
        Hbf[(size_t)(blk * 64 + rl) * 128 + nt * 8 + (col16 >> 1)] = p;
        lds_u[rl * 128 + nt * 8 + (col16 >> 1)] = p;
      }
    }
  }
  __syncthreads();
  // fused alphas: 512 (row,head) tasks, 2 per thread, h read from LDS
#pragma unroll
  for (int t = 0; t < 2; ++t) {
    int task = tid + t * 256;
    int rl = task >> 3, head = task & 7;
    int node = blk * 64 + rl;
    int k = node * 8 + head;
    float f[32];
    const uint4* lp = (const uint4*)(lds_u + rl * 128 + head * 16);
#pragma unroll
    for (int q = 0; q < 4; ++q) bf8(lp[q], &f[q * 8]);
    if (isA) {
      const float* l0 = attn_l + 0 * DOUT + head * NC;
      const float* r1 = attn_r + 1 * DOUT + head * NC;
      const float* l2 = attn_l + 2 * DOUT + head * NC;
      const float* r2 = attn_r + 2 * DOUT + head * NC;
      float s0 = 0, s1 = 0, s2 = 0, s3 = 0;
#pragma unroll
      for (int c = 0; c < 32; ++c) {
        s0 += f[c] * l0[c];
        s1 += f[c] * r1[c];
        s2 += f[c] * l2[c];
        s3 += f[c] * r2[c];
      }
      al0[k] = s0; ar1[k] = s1; al2[k] = s2; ar2[k] = s3;
    } else {
      const float* r0 = attn_r + 0 * DOUT + head * NC;
      const float* l1 = attn_l + 1 * DOUT + head * NC;
      float s0 = 0, s1 = 0;
#pragma unroll
      for (int c = 0; c < 32; ++c) {
        s0 += f[c] * r0[c];
        s1 += f[c] * l1[c];
      }
      ar0[k] = s0; al1[k] = s1;
    }
  }
}

// ---- one relation's normalized GAT message (one wave, 2 edges/iter) ---------
__device__ __forceinline__ void gat2(int dst, int wave, int lane, int h, int sub, int head,
                                     const int* __restrict__ cnt,
                                     const int* __restrict__ slots,
                                     const float* __restrict__ al,
                                     const float* __restrict__ ar,
                                     const uint4* __restrict__ hbf,
                                     int lds_slot[4][64], float lds_ex[4][512],
                                     float acc[8]) {
#pragma unroll
  for (int k = 0; k < 8; ++k) acc[k] = 0.f;
  int deg = cnt[dst];
  if (deg > CAP) deg = CAP;
  if (deg == 0) return;
  __threadfence_block();
  if (lane < deg) {
    int s = slots[(size_t)dst * CAP + lane];
    lds_slot[wave][lane] = s;
    float4 a0 = *(const float4*)(al + (size_t)s * 8);
    float4 a1 = *(const float4*)(al + (size_t)s * 8 + 4);
    float4 r0 = *(const float4*)(ar + (size_t)dst * 8);
    float4 r1 = *(const float4*)(ar + (size_t)dst * 8 + 4);
    float* exq = &lds_ex[wave][lane * 8];
    exq[0] = __expf(leaky(a0.x + r0.x));
    exq[1] = __expf(leaky(a0.y + r0.y));
    exq[2] = __expf(leaky(a0.z + r0.z));
    exq[3] = __expf(leaky(a0.w + r0.w));
    exq[4] = __expf(leaky(a1.x + r1.x));
    exq[5] = __expf(leaky(a1.y + r1.y));
    exq[6] = __expf(leaky(a1.z + r1.z));
    exq[7] = __expf(leaky(a1.w + r1.w));
  }
  __threadfence_block();
  float den = 0.f;
  int iters = (deg + 1) >> 1;
  for (int it = 0; it < iters; ++it) {
    int j = it * 2 + h;
    if (j < deg) {
      int sj = lds_slot[wave][j];
      float w = lds_ex[wave][j * 8 + head];
      uint4 u = hbf[(size_t)sj * 32 + sub];
      den += w;
      float f[8];
      bf8(u, f);
#pragma unroll
      for (int k = 0; k < 8; ++k) acc[k] += w * f[k];
    }
  }
#pragma unroll
  for (int k = 0; k < 8; ++k) acc[k] += __shfl_xor(acc[k], 32);
  den += __shfl_xor(den, 32);
  float inv = 1.f / den;
#pragma unroll
  for (int k = 0; k < 8; ++k) acc[k] *= inv;
}

// ---- fused: all relations + beta combine + ReLU, A and B node sets ----------
__global__ __launch_bounds__(256) void agg_combine(
    const int* __restrict__ cnt_ba, const int* __restrict__ sl_ba,
    const float* __restrict__ al1, const float* __restrict__ ar1,
    const int* __restrict__ cnt_aa, const int* __restrict__ sl_aa,
    const float* __restrict__ al2, const float* __restrict__ ar2,
    const int* __restrict__ cnt_ab, const int* __restrict__ sl_ab,
    const float* __restrict__ al0, const float* __restrict__ ar0,
    const uint4* __restrict__ hAbf, const uint4* __restrict__ hBbf,
    const float* __restrict__ rlA, const float* __restrict__ rrA,
    const float* __restrict__ rlB, const float* __restrict__ rrB,
    float* __restrict__ outp) {
  __shared__ int lds_slot[4][64];
  __shared__ float lds_ex[4][512];
  int wave = threadIdx.x >> 6, lane = threadIdx.x & 63;
  int h = lane >> 5, sub = lane & 31, head = sub >> 2;
  bool isA = blockIdx.x < (NAn / 4);
  int dst = (isA ? blockIdx.x : blockIdx.x - NAn / 4) * 4 + wave;
  float m0[8], hv[8], o[8];
  if (isA) {
    float m1[8];
    gat2(dst, wave, lane, h, sub, head, cnt_ba, sl_ba, al1, ar1, hBbf, lds_slot, lds_ex, m0);
    gat2(dst, wave, lane, h, sub, head, cnt_aa, sl_aa, al2, ar2, hAbf, lds_slot, lds_ex, m1);
    uint4 us = hAbf[(size_t)dst * 32 + sub];
    bf8(us, hv);
    const float4* rl4 = (const float4*)rlA;
    const float4* rr4 = (const float4*)rrA;
    float4 rl0 = rl4[sub * 2], rl1 = rl4[sub * 2 + 1];
    float4 rr0 = rr4[sub * 2], rr1 = rr4[sub * 2 + 1];
    float rl8[8] = {rl0.x, rl0.y, rl0.z, rl0.w, rl1.x, rl1.y, rl1.z, rl1.w};
    float rr8[8] = {rr0.x, rr0.y, rr0.z, rr0.w, rr1.x, rr1.y, rr1.z, rr1.w};
    float pbl = 0, p0 = 0, p1 = 0, p2 = 0;
#pragma unroll
    for (int k = 0; k < 8; ++k) {
      pbl += hv[k] * rl8[k];
      p0 += m0[k] * rr8[k];
      p1 += m1[k] * rr8[k];
      p2 += hv[k] * rr8[k];
    }
#pragma unroll
    for (int d = 1; d < 4; d <<= 1) {
      pbl += __shfl_xor(pbl, d);
      p0 += __shfl_xor(p0, d);
      p1 += __shfl_xor(p1, d);
      p2 += __shfl_xor(p2, d);
    }
    float b0 = leaky(pbl + p0), b1 = leaky(pbl + p1), b2 = leaky(pbl + p2);
    float mx = fmaxf(b0, fmaxf(b1, b2));
    float w0 = __expf(b0 - mx), w1 = __expf(b1 - mx), w2 = __expf(b2 - mx);
    float inv = 1.f / (w0 + w1 + w2);
    w0 *= inv; w1 *= inv; w2 *= inv;
#pragma unroll
    for (int k = 0; k < 8; ++k)
      o[k] = fmaxf(0.f, m0[k] * w0 + m1[k] * w1 + hv[k] * w2);
  } else {
    gat2(dst, wave, lane, h, sub, head, cnt_ab, sl_ab, al0, ar0, hAbf, lds_slot, lds_ex, m0);
    uint4 us = hBbf[(size_t)dst * 32 + sub];
    bf8(us, hv);
    const float4* rl4 = (const float4*)rlB;
    const float4* rr4 = (const float4*)rrB;
    float4 rl0 = rl4[sub * 2], rl1 = rl4[sub * 2 + 1];
    float4 rr0 = rr4[sub * 2], rr1 = rr4[sub * 2 + 1];
    float rl8[8] = {rl0.x, rl0.y, rl0.z, rl0.w, rl1.x, rl1.y, rl1.z, rl1.w};
    float rr8[8] = {rr0.x, rr0.y, rr0.z, rr0.w, rr1.x, rr1.y, rr1.z, rr1.w};
    float pbl = 0, p0 = 0, p1 = 0;
#pragma unroll
    for (int k = 0; k < 8; ++k) {
      pbl += hv[k] * rl8[k];
      p0 += m0[k] * rr8[k];
      p1 += hv[k] * rr8[k];
    }
#pragma unroll
    for (int d = 1; d < 4; d <<= 1) {
      pbl += __shfl_xor(pbl, d);
      p0 += __shfl_xor(p0, d);
      p1 += __shfl_xor(p1, d);
    }
    float b0 = leaky(pbl + p0), b1 = leaky(pbl + p1);
    float mx = fmaxf(b0, b1);
    float w0 = __expf(b0 - mx), w1 = __expf(b1 - mx);
    float inv = 1.f / (w0 + w1);
    w0 *= inv; w1 *= inv;
#pragma unroll
    for (int k = 0; k < 8; ++k) o[k] = fmaxf(0.f, m0[k] * w0 + hv[k] * w1);
  }
  float* orow = outp + (size_t)(isA ? dst : NAn + dst) * DOUT + sub * 8;
  if (h == 0) {
    *(float4*)orow = (float4){o[0], o[1], o[2], o[3]};
    *(float4*)(orow + 4) = (float4){o[4], o[5], o[6], o[7]};
  }
}

extern "C" void kernel_launch(void* const* d_in, const int* in_sizes, int n_in, void* d_out,
                              int out_size, void* d_ws, size_t ws_size, hipStream_t stream) {
  const float* xA = (const float*)d_in[0];
  const float* xB = (const float*)d_in[1];
  const int* e_ab = (const int*)d_in[2];
  const int* e_ba = (const int*)d_in[3];
  const int* e_aa = (const int*)d_in[4];
  const float* WA = (const float*)d_in[5];
  const float* bA = (const float*)d_in[6];
  const float* WB = (const float*)d_in[7];
  const float* bB = (const float*)d_in[8];
  const float* attn_l = (const float*)d_in[9];
  const float* attn_r = (const float*)d_in[10];
  const float* rlA = (const float*)d_in[11];
  const float* rrA = (const float*)d_in[12];
  const float* rlB = (const float*)d_in[13];
  const float* rrB = (const float*)d_in[14];
  float* out = (float*)d_out;

  char* p = (char*)d_ws;
  auto alloc = [&](size_t bytes) -> char* {
    char* r = p;
    p += (bytes + 255) & ~(size_t)255;
    return r;
  };
  unsigned* hAbf = (unsigned*)alloc((size_t)NAn * DOUT * 2);
  unsigned* hBbf = (unsigned*)alloc((size_t)NBn * DOUT * 2);
  float* al0 = (float*)alloc((size_t)NAn * NH * 4);
  float* ar1 = (float*)alloc((size_t)NAn * NH * 4);
  float* al2 = (float*)alloc((size_t)NAn * NH * 4);
  float* ar2 = (float*)alloc((size_t)NAn * NH * 4);
  float* ar0 = (float*)alloc((size_t)NBn * NH * 4);
  float* al1 = (float*)alloc((size_t)NBn * NH * 4);
  short8* WAhi = (short8*)alloc((size_t)8192 * 16);
  short8* WBhi = (short8*)alloc((size_t)8192 * 16);
  int* cnts = (int*)alloc((size_t)3 * NAn * 4);
  int* cnt_ba = cnts;
  int* cnt_aa = cnts + NAn;
  int* cnt_ab = cnts + 2 * NAn;
  int* slots_ba = (int*)alloc((size_t)NAn * CAP * 4);
  int* slots_aa = (int*)alloc((size_t)NAn * CAP * 4);
  int* slots_ab = (int*)alloc((size_t)NBn * CAP * 4);

  wswz<<<64, 256, 0, stream>>>(WA, WB, WAhi, WBhi, cnts);
  gemm_csr<<<GEMMB + CSRB, 256, 0, stream>>>(
      xA, xB, WAhi, WBhi, bA, bB, attn_l, attn_r, hAbf, hBbf, al0, ar1, al2, ar2, ar0, al1,
      e_ba, e_aa, e_ab, cnt_ba, cnt_aa, cnt_ab, slots_ba, slots_aa, slots_ab);
  agg_combine<<<(NAn + NBn) / 4, 256, 0, stream>>>(
      cnt_ba, slots_ba, al1, ar1, cnt_aa, slots_aa, al2, ar2, cnt_ab, slots_ab, al0, ar0,
      (const uint4*)hAbf, (const uint4*)hBbf, rlA, rrA, rlB, rrB, out);
}

// Round 8
// 390.069 us; speedup vs baseline: 1.2185x; 1.2185x over previous
//
#include <hip/hip_runtime.h>
#include <math.h>

#define NAn 40000
#define NBn 40000
#define DIN 256
#define DOUT 256
#define NH 8
#define NC 32
#define NE 400000
#define CAP 64
#define GEMMB ((NAn + NBn) / 64)          // 1250 gemm blocks
#define CSRB ((3 * NE + 255) / 256)       // 4688 csr blocks

typedef __attribute__((ext_vector_type(8))) short short8;
typedef __attribute__((ext_vector_type(4))) float floatx4;

__device__ __forceinline__ float leaky(float x) { return x > 0.f ? x : 0.2f * x; }
__device__ __forceinline__ float dot4(float4 a, float4 b) {
  return a.x * b.x + a.y * b.y + a.z * b.z + a.w * b.w;
}
__device__ __forceinline__ unsigned bf16_rne_bits(float x) {
  unsigned u = __float_as_uint(x);
  unsigned r = u + 0x7fffu + ((u >> 16) & 1u);
  return r & 0xffff0000u;
}
__device__ __forceinline__ float4 bf4(uint2 u) {
  float4 f;
  f.x = __uint_as_float(u.x << 16);
  f.y = __uint_as_float(u.x & 0xffff0000u);
  f.z = __uint_as_float(u.y << 16);
  f.w = __uint_as_float(u.y & 0xffff0000u);
  return f;
}
__device__ __forceinline__ void bf8(uint4 u, float* f) {
  f[0] = __uint_as_float(u.x << 16);
  f[1] = __uint_as_float(u.x & 0xffff0000u);
  f[2] = __uint_as_float(u.y << 16);
  f[3] = __uint_as_float(u.y & 0xffff0000u);
  f[4] = __uint_as_float(u.z << 16);
  f[5] = __uint_as_float(u.z & 0xffff0000u);
  f[6] = __uint_as_float(u.w << 16);
  f[7] = __uint_as_float(u.w & 0xffff0000u);
}

// ---- W fp32 -> swizzled bf16 B-fragments (hi only; both matrices) -----------
// Also zeroes the 3*NAn csr counters (consumed by the csr half of gemm_csr,
// which only launches after this kernel completes).
__global__ void wswz(const float* __restrict__ WA, const float* __restrict__ WB,
                     short8* __restrict__ hiA, short8* __restrict__ hiB,
                     int* __restrict__ cnts) {
  int t = blockIdx.x * blockDim.x + threadIdx.x;
  for (int i = t; i < 3 * NAn; i += 16384) cnts[i] = 0;
  const float* W;
  short8* hi;
  int tt = t;
  if (tt < 8192) {
    W = WA; hi = hiA;
  } else {
    tt -= 8192;
    if (tt >= 8192) return;
    W = WB; hi = hiB;
  }
  int kt = tt >> 10, nt = (tt >> 6) & 15, l = tt & 63;
  int n = nt * 16 + (l & 15);
  int kb = kt * 32 + (l >> 4) * 8;
  short8 h8;
#pragma unroll
  for (int j = 0; j < 8; ++j) {
    float w = W[(size_t)(kb + j) * DOUT + n];
    h8[j] = (short)(bf16_rne_bits(w) >> 16);
  }
  hi[tt] = h8;
}

// ---- FUSED: edge bucketing (blocks 0..CSRB-1) + MFMA GEMM (the rest) --------
// csr first: its 4688 short blocks flood the CUs immediately and stream at
// their atomic-throughput limit; gemm's 1250 LDS-limited blocks backfill into
// the csr drain so gemm's ~30 us hides under the csr stream instead of
// serializing at the head. NO launch_bounds cap: R7 showed capping to 5
// waves/EU spills acc/AH/AL to scratch (VGPR 48, +144 MB writes, 2x time).
__global__ __launch_bounds__(256) void gemm_csr(
    const float* __restrict__ XA, const float* __restrict__ XB,
    const short8* __restrict__ WAhi, const short8* __restrict__ WBhi,
    const float* __restrict__ bA, const float* __restrict__ bB,
    unsigned* __restrict__ HAbf, unsigned* __restrict__ HBbf,
    const int* __restrict__ e_ba, const int* __restrict__ e_aa,
    const int* __restrict__ e_ab, int* __restrict__ cnt_ba,
    int* __restrict__ cnt_aa, int* __restrict__ cnt_ab,
    int* __restrict__ sl_ba, int* __restrict__ sl_aa, int* __restrict__ sl_ab) {
  if (blockIdx.x < CSRB) {
    // ---------------- csr segment (short, no LDS use) ----------------
    int i = blockIdx.x * 256 + threadIdx.x;
    if (i >= 3 * NE) return;
    const int* e;
    int* cnt;
    int* sl;
    int k = i;
    if (i < NE) {
      e = e_ba; cnt = cnt_ba; sl = sl_ba;
    } else if (i < 2 * NE) {
      e = e_aa; cnt = cnt_aa; sl = sl_aa; k = i - NE;
    } else {
      e = e_ab; cnt = cnt_ab; sl = sl_ab; k = i - 2 * NE;
    }
    int src = e[k];
    int dst = e[NE + k];
    int pos = atomicAdd(&cnt[dst], 1);
    if (pos < CAP) sl[(size_t)dst * CAP + pos] = src;
    return;
  }
  // ---------------- gemm segment (hoisted-X R5 body, verbatim) ----------------
  __shared__ short8 bfrag[2][1024];  // 2 x 16 KB
  int blk = blockIdx.x - CSRB;
  const float* X;
  const short8* Wh;
  const float* bias;
  unsigned* Hbf;
  if (blk < NAn / 64) {
    X = XA; Wh = WAhi; bias = bA; Hbf = HAbf;
  } else {
    blk -= NAn / 64;
    X = XB; Wh = WBhi; bias = bB; Hbf = HBbf;
  }
  const int tid = threadIdx.x;
  const int lane = tid & 63, wave = tid >> 6;
  const int row0 = blk * 64 + wave * 16;
  const int col16 = lane & 15, quad = lane >> 4;

  const float4* xp = (const float4*)(X + (size_t)(row0 + col16) * DIN) + quad * 2;
  const uint4* wsrc = (const uint4*)Wh;

  uint4 pre[4];
#pragma unroll
  for (int c = 0; c < 4; ++c) pre[c] = wsrc[c * 256 + tid];

  float4 xf[16];
#pragma unroll
  for (int j = 0; j < 16; ++j) xf[j] = xp[(j >> 1) * 8 + (j & 1)];

  {
    uint4* d = (uint4*)&bfrag[0][0];
#pragma unroll
    for (int c = 0; c < 4; ++c) d[c * 256 + tid] = pre[c];
  }

  short8 AH[8], AL[8];
#pragma unroll
  for (int kt = 0; kt < 8; ++kt) {
    float xv[8] = {xf[2 * kt].x,     xf[2 * kt].y,     xf[2 * kt].z,     xf[2 * kt].w,
                   xf[2 * kt + 1].x, xf[2 * kt + 1].y, xf[2 * kt + 1].z, xf[2 * kt + 1].w};
#pragma unroll
    for (int j = 0; j < 8; ++j) {
      unsigned hb = bf16_rne_bits(xv[j]);
      AH[kt][j] = (short)(hb >> 16);
      float rem = xv[j] - __uint_as_float(hb);
      AL[kt][j] = (short)(bf16_rne_bits(rem) >> 16);
    }
  }

  floatx4 acc[16];
#pragma unroll
  for (int i = 0; i < 16; ++i) acc[i] = (floatx4){0.f, 0.f, 0.f, 0.f};
  __syncthreads();

#pragma unroll
  for (int kt = 0; kt < 8; ++kt) {
    if (kt < 7) {
      const uint4* s = wsrc + (size_t)(kt + 1) * 1024;
#pragma unroll
      for (int c = 0; c < 4; ++c) pre[c] = s[c * 256 + tid];
    }
    const short8* bp = &bfrag[kt & 1][0];
#pragma unroll
    for (int nt = 0; nt < 16; ++nt) {
      short8 bv = bp[nt * 64 + lane];  // ds_read_b128
      acc[nt] = __builtin_amdgcn_mfma_f32_16x16x32_bf16(AH[kt], bv, acc[nt], 0, 0, 0);
      acc[nt] = __builtin_amdgcn_mfma_f32_16x16x32_bf16(AL[kt], bv, acc[nt], 0, 0, 0);
    }
    if (kt < 7) {
      uint4* d = (uint4*)&bfrag[(kt + 1) & 1][0];
#pragma unroll
      for (int c = 0; c < 4; ++c) d[c * 256 + tid] = pre[c];
    }
    __syncthreads();
  }
#pragma unroll
  for (int nt = 0; nt < 16; ++nt) {
    float bcol = bias[nt * 16 + col16];
#pragma unroll
    for (int r = 0; r < 4; ++r) {
      int row = row0 + quad * 4 + r;
      float v = acc[nt][r] + bcol;
      float vp = __shfl_xor(v, 1);
      if ((lane & 1) == 0) {
        unsigned p = (bf16_rne_bits(v) >> 16) | bf16_rne_bits(vp);
        Hbf[(size_t)row * 128 + nt * 8 + (col16 >> 1)] = p;
      }
    }
  }
}

// ---- per-(node,head) attention scalars, bf16 h, both node sets --------------
__global__ void alphas(const uint2* __restrict__ hAbf, const uint2* __restrict__ hBbf,
                       const float* __restrict__ attn_l, const float* __restrict__ attn_r,
                       float* __restrict__ al0, float* __restrict__ ar1,
                       float* __restrict__ al2, float* __restrict__ ar2,
                       float* __restrict__ ar0, float* __restrict__ al1) {
  int idx = blockIdx.x * blockDim.x + threadIdx.x;
  if (idx >= (NAn + NBn) * NH) return;
  bool isA = idx < NAn * NH;
  int k = isA ? idx : idx - NAn * NH;
  int head = k & 7;
  const uint2* h8 = (isA ? hAbf : hBbf) + (size_t)k * 8;
  if (isA) {
    const float4* l0 = (const float4*)(attn_l + 0 * DOUT + head * NC);
    const float4* r1 = (const float4*)(attn_r + 1 * DOUT + head * NC);
    const float4* l2 = (const float4*)(attn_l + 2 * DOUT + head * NC);
    const float4* r2 = (const float4*)(attn_r + 2 * DOUT + head * NC);
    float s0 = 0, s1 = 0, s2 = 0, s3 = 0;
#pragma unroll
    for (int q = 0; q < 8; ++q) {
      float4 hv = bf4(h8[q]);
      s0 += dot4(hv, l0[q]);
      s1 += dot4(hv, r1[q]);
      s2 += dot4(hv, l2[q]);
      s3 += dot4(hv, r2[q]);
    }
    al0[k] = s0;
    ar1[k] = s1;
    al2[k] = s2;
    ar2[k] = s3;
  } else {
    const float4* r0 = (const float4*)(attn_r + 0 * DOUT + head * NC);
    const float4* l1 = (const float4*)(attn_l + 1 * DOUT + head * NC);
    float s0 = 0, s1 = 0;
#pragma unroll
    for (int q = 0; q < 8; ++q) {
      float4 hv = bf4(h8[q]);
      s0 += dot4(hv, r0[q]);
      s1 += dot4(hv, l1[q]);
    }
    ar0[k] = s0;
    al1[k] = s1;
  }
}

// ---- one relation's normalized GAT message (one wave, 2 edges/iter) ---------
__device__ __forceinline__ void gat2(int dst, int wave, int lane, int h, int sub, int head,
                                     const int* __restrict__ cnt,
                                     const int* __restrict__ slots,
                                     const float* __restrict__ al,
                                     const float* __restrict__ ar,
                                     const uint4* __restrict__ hbf,
                                     int lds_slot[4][64], float lds_ex[4][512],
                                     float acc[8]) {
#pragma unroll
  for (int k = 0; k < 8; ++k) acc[k] = 0.f;
  int deg = cnt[dst];
  if (deg > CAP) deg = CAP;
  if (deg == 0) return;
  __threadfence_block();
  if (lane < deg) {
    int s = slots[(size_t)dst * CAP + lane];
    lds_slot[wave][lane] = s;
    float4 a0 = *(const float4*)(al + (size_t)s * 8);
    float4 a1 = *(const float4*)(al + (size_t)s * 8 + 4);
    float4 r0 = *(const float4*)(ar + (size_t)dst * 8);
    float4 r1 = *(const float4*)(ar + (size_t)dst * 8 + 4);
    float* exq = &lds_ex[wave][lane * 8];
    exq[0] = __expf(leaky(a0.x + r0.x));
    exq[1] = __expf(leaky(a0.y + r0.y));
    exq[2] = __expf(leaky(a0.z + r0.z));
    exq[3] = __expf(leaky(a0.w + r0.w));
    exq[4] = __expf(leaky(a1.x + r1.x));
    exq[5] = __expf(leaky(a1.y + r1.y));
    exq[6] = __expf(leaky(a1.z + r1.z));
    exq[7] = __expf(leaky(a1.w + r1.w));
  }
  __threadfence_block();
  float den = 0.f;
  int iters = (deg + 1) >> 1;
  for (int it = 0; it < iters; ++it) {
    int j = it * 2 + h;
    if (j < deg) {
      int sj = lds_slot[wave][j];
      float w = lds_ex[wave][j * 8 + head];
      uint4 u = hbf[(size_t)sj * 32 + sub];
      den += w;
      float f[8];
      bf8(u, f);
#pragma unroll
      for (int k = 0; k < 8; ++k) acc[k] += w * f[k];
    }
  }
#pragma unroll
  for (int k = 0; k < 8; ++k) acc[k] += __shfl_xor(acc[k], 32);
  den += __shfl_xor(den, 32);
  float inv = 1.f / den;
#pragma unroll
  for (int k = 0; k < 8; ++k) acc[k] *= inv;
}

// ---- fused: all relations + beta combine + ReLU, A and B node sets ----------
__global__ __launch_bounds__(256) void agg_combine(
    const int* __restrict__ cnt_ba, const int* __restrict__ sl_ba,
    const float* __restrict__ al1, const float* __restrict__ ar1,
    const int* __restrict__ cnt_aa, const int* __restrict__ sl_aa,
    const float* __restrict__ al2, const float* __restrict__ ar2,
    const int* __restrict__ cnt_ab, const int* __restrict__ sl_ab,
    const float* __restrict__ al0, const float* __restrict__ ar0,
    const uint4* __restrict__ hAbf, const uint4* __restrict__ hBbf,
    const float* __restrict__ rlA, const float* __restrict__ rrA,
    const float* __restrict__ rlB, const float* __restrict__ rrB,
    float* __restrict__ outp) {
  __shared__ int lds_slot[4][64];
  __shared__ float lds_ex[4][512];
  int wave = threadIdx.x >> 6, lane = threadIdx.x & 63;
  int h = lane >> 5, sub = lane & 31, head = sub >> 2;
  bool isA = blockIdx.x < (NAn / 4);
  int dst = (isA ? blockIdx.x : blockIdx.x - NAn / 4) * 4 + wave;
  float m0[8], hv[8], o[8];
  if (isA) {
    float m1[8];
    gat2(dst, wave, lane, h, sub, head, cnt_ba, sl_ba, al1, ar1, hBbf, lds_slot, lds_ex, m0);
    gat2(dst, wave, lane, h, sub, head, cnt_aa, sl_aa, al2, ar2, hAbf, lds_slot, lds_ex, m1);
    uint4 us = hAbf[(size_t)dst * 32 + sub];
    bf8(us, hv);
    const float4* rl4 = (const float4*)rlA;
    const float4* rr4 = (const float4*)rrA;
    float4 rl0 = rl4[sub * 2], rl1 = rl4[sub * 2 + 1];
    float4 rr0 = rr4[sub * 2], rr1 = rr4[sub * 2 + 1];
    float rl8[8] = {rl0.x, rl0.y, rl0.z, rl0.w, rl1.x, rl1.y, rl1.z, rl1.w};
    float rr8[8] = {rr0.x, rr0.y, rr0.z, rr0.w, rr1.x, rr1.y, rr1.z, rr1.w};
    float pbl = 0, p0 = 0, p1 = 0, p2 = 0;
#pragma unroll
    for (int k = 0; k < 8; ++k) {
      pbl += hv[k] * rl8[k];
      p0 += m0[k] * rr8[k];
      p1 += m1[k] * rr8[k];
      p2 += hv[k] * rr8[k];
    }
#pragma unroll
    for (int d = 1; d < 4; d <<= 1) {
      pbl += __shfl_xor(pbl, d);
      p0 += __shfl_xor(p0, d);
      p1 += __shfl_xor(p1, d);
      p2 += __shfl_xor(p2, d);
    }
    float b0 = leaky(pbl + p0), b1 = leaky(pbl + p1), b2 = leaky(pbl + p2);
    float mx = fmaxf(b0, fmaxf(b1, b2));
    float w0 = __expf(b0 - mx), w1 = __expf(b1 - mx), w2 = __expf(b2 - mx);
    float inv = 1.f / (w0 + w1 + w2);
    w0 *= inv; w1 *= inv; w2 *= inv;
#pragma unroll
    for (int k = 0; k < 8; ++k)
      o[k] = fmaxf(0.f, m0[k] * w0 + m1[k] * w1 + hv[k] * w2);
  } else {
    gat2(dst, wave, lane, h, sub, head, cnt_ab, sl_ab, al0, ar0, hAbf, lds_slot, lds_ex, m0);
    uint4 us = hBbf[(size_t)dst * 32 + sub];
    bf8(us, hv);
    const float4* rl4 = (const float4*)rlB;
    const float4* rr4 = (const float4*)rrB;
    float4 rl0 = rl4[sub * 2], rl1 = rl4[sub * 2 + 1];
    float4 rr0 = rr4[sub * 2], rr1 = rr4[sub * 2 + 1];
    float rl8[8] = {rl0.x, rl0.y, rl0.z, rl0.w, rl1.x, rl1.y, rl1.z, rl1.w};
    float rr8[8] = {rr0.x, rr0.y, rr0.z, rr0.w, rr1.x, rr1.y, rr1.z, rr1.w};
    float pbl = 0, p0 = 0, p1 = 0;
#pragma unroll
    for (int k = 0; k < 8; ++k) {
      pbl += hv[k] * rl8[k];
      p0 += m0[k] * rr8[k];
      p1 += hv[k] * rr8[k];
    }
#pragma unroll
    for (int d = 1; d < 4; d <<= 1) {
      pbl += __shfl_xor(pbl, d);
      p0 += __shfl_xor(p0, d);
      p1 += __shfl_xor(p1, d);
    }
    float b0 = leaky(pbl + p0), b1 = leaky(pbl + p1);
    float mx = fmaxf(b0, b1);
    float w0 = __expf(b0 - mx), w1 = __expf(b1 - mx);
    float inv = 1.f / (w0 + w1);
    w0 *= inv; w1 *= inv;
#pragma unroll
    for (int k = 0; k < 8; ++k) o[k] = fmaxf(0.f, m0[k] * w0 + hv[k] * w1);
  }
  float* orow = outp + (size_t)(isA ? dst : NAn + dst) * DOUT + sub * 8;
  if (h == 0) {
    *(float4*)orow = (float4){o[0], o[1], o[2], o[3]};
    *(float4*)(orow + 4) = (float4){o[4], o[5], o[6], o[7]};
  }
}

extern "C" void kernel_launch(void* const* d_in, const int* in_sizes, int n_in, void* d_out,
                              int out_size, void* d_ws, size_t ws_size, hipStream_t stream) {
  const float* xA = (const float*)d_in[0];
  const float* xB = (const float*)d_in[1];
  const int* e_ab = (const int*)d_in[2];
  const int* e_ba = (const int*)d_in[3];
  const int* e_aa = (const int*)d_in[4];
  const float* WA = (const float*)d_in[5];
  const float* bA = (const float*)d_in[6];
  const float* WB = (const float*)d_in[7];
  const float* bB = (const float*)d_in[8];
  const float* attn_l = (const float*)d_in[9];
  const float* attn_r = (const float*)d_in[10];
  const float* rlA = (const float*)d_in[11];
  const float* rrA = (const float*)d_in[12];
  const float* rlB = (const float*)d_in[13];
  const float* rrB = (const float*)d_in[14];
  float* out = (float*)d_out;

  char* p = (char*)d_ws;
  auto alloc = [&](size_t bytes) -> char* {
    char* r = p;
    p += (bytes + 255) & ~(size_t)255;
    return r;
  };
  unsigned* hAbf = (unsigned*)alloc((size_t)NAn * DOUT * 2);
  unsigned* hBbf = (unsigned*)alloc((size_t)NBn * DOUT * 2);
  float* al0 = (float*)alloc((size_t)NAn * NH * 4);
  float* ar1 = (float*)alloc((size_t)NAn * NH * 4);
  float* al2 = (float*)alloc((size_t)NAn * NH * 4);
  float* ar2 = (float*)alloc((size_t)NAn * NH * 4);
  float* ar0 = (float*)alloc((size_t)NBn * NH * 4);
  float* al1 = (float*)alloc((size_t)NBn * NH * 4);
  short8* WAhi = (short8*)alloc((size_t)8192 * 16);
  short8* WBhi = (short8*)alloc((size_t)8192 * 16);
  int* cnts = (int*)alloc((size_t)3 * NAn * 4);
  int* cnt_ba = cnts;
  int* cnt_aa = cnts + NAn;
  int* cnt_ab = cnts + 2 * NAn;
  int* slots_ba = (int*)alloc((size_t)NAn * CAP * 4);
  int* slots_aa = (int*)alloc((size_t)NAn * CAP * 4);
  int* slots_ab = (int*)alloc((size_t)NBn * CAP * 4);

  wswz<<<64, 256, 0, stream>>>(WA, WB, WAhi, WBhi, cnts);
  gemm_csr<<<GEMMB + CSRB, 256, 0, stream>>>(
      xA, xB, WAhi, WBhi, bA, bB, hAbf, hBbf, e_ba, e_aa, e_ab, cnt_ba, cnt_aa, cnt_ab,
      slots_ba, slots_aa, slots_ab);
  alphas<<<((NAn + NBn) * NH + 255) / 256, 256, 0, stream>>>(
      (const uint2*)hAbf, (const uint2*)hBbf, attn_l, attn_r, al0, ar1, al2, ar2, ar0, al1);
  agg_combine<<<(NAn + NBn) / 4, 256, 0, stream>>>(
      cnt_ba, slots_ba, al1, ar1, cnt_aa, slots_aa, al2, ar2, cnt_ab, slots_ab, al0, ar0,
      (const uint4*)hAbf, (const uint4*)hBbf, rlA, rrA, rlB, rrB, out);
}